// Round 1
// 2097.119 us; speedup vs baseline: 1.1773x; 1.1773x over previous
//
#include <hip/hip_runtime.h>

typedef unsigned short u16;
typedef __attribute__((ext_vector_type(8))) short frag8;
typedef __attribute__((ext_vector_type(4))) float f32x4;
typedef __attribute__((ext_vector_type(8))) unsigned short u16x8;

// address-space typedefs for global_load_lds
typedef __attribute__((address_space(1))) const void GV;
typedef __attribute__((address_space(3))) void LV;

__device__ __forceinline__ void gl16(const u16* g, u16* l) {
  // async global->LDS, 16B per lane; LDS dest = wave-uniform base + lane*16
  __builtin_amdgcn_global_load_lds((GV*)g, (LV*)l, 16, 0, 0);
}

__device__ __forceinline__ float b2f(u16 u) {
  union { unsigned int i; float f; } v; v.i = ((unsigned int)u) << 16; return v.f;
}
__device__ __forceinline__ u16 f2b(float f) {
  union { float f; unsigned int i; } v; v.f = f;
  unsigned int x = v.i;
  x += 0x7fffu + ((x >> 16) & 1u);
  return (u16)(x >> 16);
}

// ---------------------------------------------------------------------------
// Prep kernels — f32 inputs; everything GEMM-facing becomes bf16 once here.
// ---------------------------------------------------------------------------
__global__ void cvt3(const float* __restrict__ s0, const float* __restrict__ s1,
                     const float* __restrict__ s2, u16* __restrict__ d0,
                     u16* __restrict__ d1, u16* __restrict__ d2) {
  int i = blockIdx.x * 256 + threadIdx.x;   // 3 * 3145728
  int which = i / 3145728;
  int j = i - which * 3145728;
  const float* s = (which == 0) ? s0 : (which == 1 ? s1 : s2);
  u16* d = (which == 0) ? d0 : (which == 1 ? d1 : d2);
  d[j] = f2b(s[j]);
}

__global__ void cvt2(const float* __restrict__ s0, const float* __restrict__ s1,
                     u16* __restrict__ d0, u16* __restrict__ d1) {
  int i = blockIdx.x * 256 + threadIdx.x;   // 2 * 1048576
  if (i < 1048576) d0[i] = f2b(s0[i]);
  else             d1[i - 1048576] = f2b(s1[i - 1048576]);
}

// Split g1_wih [3072, 642] (f32) into bf16 Wc [3072,512] and Wd [3072,192]
// (zero-padded cols 130..191 so K is a multiple of BK=32 twice over).
__global__ void prep_w1(const float* __restrict__ wih, u16* __restrict__ Wc, u16* __restrict__ Wd) {
  int i = blockIdx.x * 256 + threadIdx.x;
  const int NC = 3072 * 512;
  const int ND = 3072 * 192;
  if (i < NC) {
    int n = i >> 9, k = i & 511;
    Wc[i] = f2b(wih[n * 642 + k]);
  } else if (i < NC + ND) {
    int j = i - NC;
    int n = j / 192, k = j - n * 192;
    Wd[j] = (k < 130) ? f2b(wih[n * 642 + 512 + k]) : (u16)0;
  }
}

// fco_w [130,1024] f32 -> bf16 WBy [256,1024], zero rows 130..255
__global__ void prep_wby(const float* __restrict__ fcow, u16* __restrict__ wby) {
  int i = blockIdx.x * 256 + threadIdx.x;   // 256*1024
  int n = i >> 10;
  wby[i] = (n < 130) ? f2b(fcow[i]) : (u16)0;
}

// ---------------------------------------------------------------------------
// bt-GEMM: C[m][n] = sum_k A[m][k]*Bsel[n'][k].  A,B bf16.
//   Bsel/n' per 128-tile: n0<n_split -> B0,n'=n else B1,n'=n-n_split
// 128x128 tile, BK=32, 512 threads = 8 waves (4m x 2n of 32m x 64n, acc 2x4).
// r7: staging via __builtin_amdgcn_global_load_lds width=16 (m151: +35% over
// reg-staging), LDS linear [128][32] (64B rows -> b128 frag reads are
// bucket-optimal: 8 lanes per 4-bank group = LDS BW floor; the old LDST=36
// padding produced ragged 2-bank-offset windows = 3.1M conflict cyc/dispatch).
// Single-buffer (explicit dbuf was 1.5x WORSE in r6: occupancy). mfma
// 16x16x32 bf16, fp32 accum (AGPR).
// UDA=true variant: A built from target[B=128,T=256,D=130] f32 with the
// prev-shift, reg-staged + ds_write (needs f2b); kept as a SEPARATE template
// instantiation so the hot kernel's regalloc isn't polluted.
//   tstep >= 0: M=2048, time step = tstep (fallback path)
//   tstep <  0: M=32768, row gm -> t = gm>>11, m2 = gm&2047 (precompute-all)
// Epilogue modes:
//  0: out0(bf16)[m*N+n] = acc + bias0[n]
//  1: t=tanh(acc+bias0[n]); n<1024 -> h1 else h2; write f32 (fout*) AND bf16 (out*)
//  2: out0(bf16)[m*N+n] = acc + b2f(addmat[(m&2047)*N+n])             [N=3072]
//  3: n<3072 -> out0+bias0 (gi2) ; else out1+bias1 (gh1)              [N=6144]
//  4: n<3072 -> out0+bias0 (gh2) ; 3072<=n<3202 -> y(f32) scatter     [N=3328]
// ---------------------------------------------------------------------------
template <bool UDA>
__global__ __launch_bounds__(512, 6) void gemm_bt(
    const u16* __restrict__ A, int lda, const float* __restrict__ dA,
    const u16* __restrict__ B0, const u16* __restrict__ B1, int ldb, int n_split,
    int N, int K, int mode, int tstep,
    const float* __restrict__ bias0, const float* __restrict__ bias1,
    u16* __restrict__ out0, u16* __restrict__ out1,
    const u16* __restrict__ addmat,
    float* __restrict__ fout0, float* __restrict__ fout1)
{
  __shared__ u16 As[128 * 32];
  __shared__ u16 Bs[128 * 32];

  const int tid = threadIdx.x;
  const int wave = tid >> 6;
  const int lane = tid & 63;
  const int m0 = blockIdx.y * 128;
  const int n0 = blockIdx.x * 128;
  const int wm = (wave & 3) * 32;    // wave m-offset (4 waves down)
  const int wn = (wave >> 2) * 64;   // wave n-offset (2 waves across)
  const int lr = lane & 15;
  const int lq = lane >> 4;

  const u16* Bsel;
  int nb0;
  if (n0 < n_split) { Bsel = B0; nb0 = n0; }
  else              { Bsel = B1; nb0 = n0 - n_split; }

  f32x4 acc[2][4] = {};

  // global_load_lds staging: wave w owns rows [w*16, w*16+16);
  // lane l -> row w*16 + (l>>2), 16B chunk (l&3)*8 elems. LDS dest is the
  // wave-uniform base &Xs[w*512]; HW scatters base + lane*16 = linear match.
  const int srow_g = wave * 16 + (lane >> 2);
  const int scol_g = (lane & 3) * 8;
  const u16* gB = &Bsel[(size_t)(nb0 + srow_g) * ldb + scol_g];
  u16* lB = &Bs[wave * 512];
  const u16* gA = UDA ? nullptr : &A[(size_t)(m0 + srow_g) * lda + scol_g];
  u16* lA = &As[wave * 512];

  // reg-staging coords for the UDA path (512 threads cover 128x32 tile)
  const int srow = tid >> 2;
  const int skc  = (tid & 3) * 8;

  for (int k0 = 0; k0 < K; k0 += 32) {
    if constexpr (UDA) {
      // A from target (f32, prev-shifted, zero-padded k>=130 / t==0)
      int mrow = m0 + srow;
      int t  = (tstep >= 0) ? tstep : (mrow >> 11);
      int m2 = mrow & 2047;
      int e = m2 >> 7, b = m2 & 127;
      int tt = e * 16 + t;
      const float* trow = dA + (size_t)(b * 256 + tt - 1) * 130;
      int kb = k0 + skc;
      u16x8 ra;
      if (tt > 0 && kb + 8 <= 130) {
#pragma unroll
        for (int q = 0; q < 4; ++q) {
          float2 v = *(const float2*)&trow[kb + 2 * q];
          ra[2 * q] = f2b(v.x); ra[2 * q + 1] = f2b(v.y);
        }
      } else {
#pragma unroll
        for (int j = 0; j < 8; ++j) {
          int k = kb + j;
          float v = (tt > 0 && k < 130) ? trow[k] : 0.f;
          ra[j] = f2b(v);
        }
      }
      *(u16x8*)&As[srow * 32 + skc] = ra;
    } else {
      gl16(gA + k0, lA);
    }
    gl16(gB + k0, lB);
    __syncthreads();   // compiler drains vmcnt/lgkm before s_barrier

    frag8 af[2], bfr[4];
#pragma unroll
    for (int i = 0; i < 2; ++i)
      af[i] = *(const frag8*)&As[(wm + i * 16 + lr) * 32 + lq * 8];
#pragma unroll
    for (int j = 0; j < 4; ++j)
      bfr[j] = *(const frag8*)&Bs[(wn + j * 16 + lr) * 32 + lq * 8];
#pragma unroll
    for (int i = 0; i < 2; ++i)
#pragma unroll
      for (int j = 0; j < 4; ++j)
        acc[i][j] = __builtin_amdgcn_mfma_f32_16x16x32_bf16(af[i], bfr[j], acc[i][j], 0, 0, 0);
    __syncthreads();
  }

  // C/D layout: col = lane&15 (n), row = (lane>>4)*4 + reg (m).
#pragma unroll
  for (int i = 0; i < 2; ++i) {
#pragma unroll
    for (int r = 0; r < 4; ++r) {
      int m = m0 + wm + i * 16 + lq * 4 + r;
#pragma unroll
      for (int j = 0; j < 4; ++j) {
        int n = n0 + wn + j * 16 + lr;
        float v = acc[i][j][r];
        if (mode == 0) {
          out0[(size_t)m * N + n] = f2b(v + bias0[n]);
        } else if (mode == 1) {
          float t = tanhf(v + bias0[n]);
          if (n < 1024) { fout0[(size_t)m * 1024 + n] = t;          out0[(size_t)m * 1024 + n] = f2b(t); }
          else          { fout1[(size_t)m * 1024 + (n - 1024)] = t; out1[(size_t)m * 1024 + (n - 1024)] = f2b(t); }
        } else if (mode == 2) {
          out0[(size_t)m * N + n] = f2b(v + b2f(addmat[(size_t)(m & 2047) * N + n]));
        } else if (mode == 3) {
          if (n < 3072) out0[(size_t)m * 3072 + n] = f2b(v + bias0[n]);
          else          out1[(size_t)m * 3072 + (n - 3072)] = f2b(v + bias1[n - 3072]);
        } else { // mode 4
          if (n < 3072) {
            out0[(size_t)m * 3072 + n] = f2b(v + bias0[n]);
          } else if (n < 3202) {
            int d = n - 3072;
            int b = m & 127, e = m >> 7;
            fout0[(size_t)((b << 8) + (e << 4) + tstep) * 130 + d] = v + bias1[d];
          }
        }
      }
    }
  }
}

// ---------------------------------------------------------------------------
// GRU combine: h = (1-z)*n + z*h. gi/gh bf16 [2048,3072] (biases folded),
// h32 f32 [2048,1024] master state (in place), hb16 bf16 shadow for GEMM A.
// ---------------------------------------------------------------------------
__global__ __launch_bounds__(256) void gru_combine(
    const u16* __restrict__ gi, const u16* __restrict__ gh,
    float* __restrict__ h32, u16* __restrict__ hb16)
{
  int idx = blockIdx.x * 256 + threadIdx.x;   // 0 .. 2048*128-1
  int m = idx >> 7;
  int j0 = (idx & 127) << 3;
  const size_t gb = (size_t)m * 3072 + j0;
  const size_t hb = (size_t)m * 1024 + j0;
  u16x8 ir = *(const u16x8*)&gi[gb];
  u16x8 iz = *(const u16x8*)&gi[gb + 1024];
  u16x8 in_ = *(const u16x8*)&gi[gb + 2048];
  u16x8 hr = *(const u16x8*)&gh[gb];
  u16x8 hz = *(const u16x8*)&gh[gb + 1024];
  u16x8 hn = *(const u16x8*)&gh[gb + 2048];
  f32x4 h0 = *(const f32x4*)&h32[hb];
  f32x4 h1v = *(const f32x4*)&h32[hb + 4];
  f32x4 o0, o1;
  u16x8 ob;
#pragma unroll
  for (int q = 0; q < 8; ++q) {
    float r = 1.f / (1.f + __expf(-(b2f(ir[q]) + b2f(hr[q]))));
    float z = 1.f / (1.f + __expf(-(b2f(iz[q]) + b2f(hz[q]))));
    float nn = tanhf(b2f(in_[q]) + r * b2f(hn[q]));
    float hh = (q < 4) ? h0[q & 3] : h1v[q & 3];
    float res = (1.f - z) * nn + z * hh;
    if (q < 4) o0[q & 3] = res; else o1[q & 3] = res;
    ob[q] = f2b(res);
  }
  *(f32x4*)&h32[hb] = o0;
  *(f32x4*)&h32[hb + 4] = o1;
  *(u16x8*)&hb16[hb] = ob;
}

// ---------------------------------------------------------------------------
extern "C" void kernel_launch(void* const* d_in, const int* in_sizes, int n_in,
                              void* d_out, int out_size, void* d_ws, size_t ws_size,
                              hipStream_t stream)
{
  const float* c      = (const float*)d_in[0];
  const float* target = (const float*)d_in[1];
  const float* fiw    = (const float*)d_in[4];
  const float* fib    = (const float*)d_in[5];
  const float* g1wih  = (const float*)d_in[6];
  const float* g1whh  = (const float*)d_in[7];
  const float* g1bih  = (const float*)d_in[8];
  const float* g1bhh  = (const float*)d_in[9];
  const float* g2wih  = (const float*)d_in[10];
  const float* g2whh  = (const float*)d_in[11];
  const float* g2bih  = (const float*)d_in[12];
  const float* g2bhh  = (const float*)d_in[13];
  const float* fcow   = (const float*)d_in[14];
  const float* fcob   = (const float*)d_in[15];
  float* out = (float*)d_out;

  char* wsp = (char*)d_ws;
  size_t off = 0;
  auto takeb = [&](size_t bytes) {
    void* p = (void*)(wsp + off);
    off += bytes;
    off = (off + 255) & ~(size_t)255;
    return p;
  };
  float* h1f = (float*)takeb((size_t)2048 * 1024 * 4);
  float* h2f = (float*)takeb((size_t)2048 * 1024 * 4);
  u16* h1b   = (u16*)takeb((size_t)2048 * 1024 * 2);
  u16* h2b   = (u16*)takeb((size_t)2048 * 1024 * 2);
  u16* gic   = (u16*)takeb((size_t)2048 * 3072 * 2);
  u16* gib   = (u16*)takeb((size_t)2048 * 3072 * 2);
  u16* gh1   = (u16*)takeb((size_t)2048 * 3072 * 2);
  u16* gh2   = (u16*)takeb((size_t)2048 * 3072 * 2);
  u16* cbf   = (u16*)takeb((size_t)2048 * 512 * 2);
  u16* Wfi   = (u16*)takeb((size_t)2048 * 512 * 2);
  u16* Wc    = (u16*)takeb((size_t)3072 * 512 * 2);
  u16* Wd    = (u16*)takeb((size_t)3072 * 192 * 2);
  u16* W1h   = (u16*)takeb((size_t)3072 * 1024 * 2);
  u16* W2i   = (u16*)takeb((size_t)3072 * 1024 * 2);
  u16* W2h   = (u16*)takeb((size_t)3072 * 1024 * 2);
  u16* WBy   = (u16*)takeb((size_t)256 * 1024 * 2);
  // base ~99 MiB. gi1_all (all 16 timesteps of gi1, teacher-forced so
  // h-independent) costs +192 MiB — take it only if ws allows.
  const size_t GI1_BYTES = (size_t)16 * 2048 * 3072 * 2;
  u16* gi1 = nullptr;
  if (ws_size >= off + GI1_BYTES + 256) gi1 = (u16*)takeb(GI1_BYTES);
  (void)in_sizes; (void)n_in; (void)out_size;

  const int BIG = 1 << 30;   // n_split sentinel: always B0

  // --- one-time prep: conversions to bf16 ---
  cvt2<<<8192, 256, 0, stream>>>(c, fiw, cbf, Wfi);
  cvt3<<<36864, 256, 0, stream>>>(g1whh, g2wih, g2whh, W1h, W2i, W2h);
  prep_w1 <<<8448, 256, 0, stream>>>(g1wih, Wc, Wd);
  prep_wby<<<1024, 256, 0, stream>>>(fcow, WBy);

  // --- init ---
  // h1,h2 = tanh(c @ fiw.T + fib)  (f32 + bf16 shadow)
  gemm_bt<false><<<dim3(16, 16), 512, 0, stream>>>(cbf, 512, nullptr, Wfi, nullptr, 512, BIG,
                                                   2048, 512, 1, 0, fib, nullptr,
                                                   h1b, h2b, nullptr, h1f, h2f);
  // gi_c = c @ Wc.T + g1bih
  gemm_bt<false><<<dim3(24, 16), 512, 0, stream>>>(cbf, 512, nullptr, Wc, nullptr, 512, BIG,
                                                   3072, 512, 0, 0, g1bih, nullptr,
                                                   gic, nullptr, nullptr, nullptr, nullptr);
  // gh1 = h1 @ g1whh.T + g1bhh
  gemm_bt<false><<<dim3(24, 16), 512, 0, stream>>>(h1b, 1024, nullptr, W1h, nullptr, 1024, BIG,
                                                   3072, 1024, 0, 0, g1bhh, nullptr,
                                                   gh1, nullptr, nullptr, nullptr, nullptr);
  // gh2 = h2 @ g2whh.T + g2bhh
  gemm_bt<false><<<dim3(24, 16), 512, 0, stream>>>(h2b, 1024, nullptr, W2h, nullptr, 1024, BIG,
                                                   3072, 1024, 0, 0, g2bhh, nullptr,
                                                   gh2, nullptr, nullptr, nullptr, nullptr);

  // gi1 for ALL t in one GEMM (M=32768): gi1_all[t*2048+m] = prev_t @ Wd.T + gic
  if (gi1 != nullptr) {
    gemm_bt<true><<<dim3(24, 256), 512, 0, stream>>>(nullptr, 192, target, Wd, nullptr, 192, BIG,
                                                     3072, 192, 2, -1, nullptr, nullptr,
                                                     gi1, nullptr, gic, nullptr, nullptr);
  }

  // --- recurrence ---
  for (int t = 0; t < 16; ++t) {
    const u16* gi1_t;
    if (gi1 != nullptr) {
      gi1_t = gi1 + (size_t)t * 2048 * 3072;
    } else {
      // fallback: per-step gi1 (A read directly from target, shifted)
      gemm_bt<true><<<dim3(24, 16), 512, 0, stream>>>(nullptr, 192, target, Wd, nullptr, 192, BIG,
                                                      3072, 192, 2, t, nullptr, nullptr,
                                                      gib, nullptr, gic, nullptr, nullptr);
      gi1_t = gib;
    }
    gru_combine<<<1024, 256, 0, stream>>>(gi1_t, gh1, h1f, h1b);   // h1 <- GRU1
    // gi2 = h1 @ g2wih.T + g2bih ; gh1_next = h1 @ g1whh.T + g1bhh
    gemm_bt<false><<<dim3(48, 16), 512, 0, stream>>>(h1b, 1024, nullptr, W2i, W1h, 1024, 3072,
                                                     6144, 1024, 3, 0, g2bih, g1bhh,
                                                     gib, gh1, nullptr, nullptr, nullptr);
    gru_combine<<<1024, 256, 0, stream>>>(gib, gh2, h2f, h2b);     // h2 <- GRU2
    // gh2_next = h2 @ g2whh.T + g2bhh ; y = h2 @ fco_w.T + fco_b -> out (f32)
    gemm_bt<false><<<dim3(26, 16), 512, 0, stream>>>(h2b, 1024, nullptr, W2h, WBy, 1024, 3072,
                                                     3328, 1024, 4, t, g2bhh, fcob,
                                                     gh2, nullptr, nullptr, out, nullptr);
  }
}

// Round 2
// 2066.267 us; speedup vs baseline: 1.1949x; 1.0149x over previous
//
#include <hip/hip_runtime.h>

typedef unsigned short u16;
typedef __attribute__((ext_vector_type(8))) short frag8;
typedef __attribute__((ext_vector_type(4))) float f32x4;
typedef __attribute__((ext_vector_type(8))) unsigned short u16x8;

// address-space typedefs for global_load_lds
typedef __attribute__((address_space(1))) const void GV;
typedef __attribute__((address_space(3))) void LV;

__device__ __forceinline__ void gl16(const u16* g, u16* l) {
  // async global->LDS, 16B per lane; LDS dest = wave-uniform base + lane*16
  __builtin_amdgcn_global_load_lds((GV*)g, (LV*)l, 16, 0, 0);
}

__device__ __forceinline__ float b2f(u16 u) {
  union { unsigned int i; float f; } v; v.i = ((unsigned int)u) << 16; return v.f;
}
__device__ __forceinline__ u16 f2b(float f) {
  union { float f; unsigned int i; } v; v.f = f;
  unsigned int x = v.i;
  x += 0x7fffu + ((x >> 16) & 1u);
  return (u16)(x >> 16);
}

// ---------------------------------------------------------------------------
// Prep kernels — f32 inputs; everything GEMM-facing becomes bf16 once here.
// ---------------------------------------------------------------------------
__global__ void cvt3(const float* __restrict__ s0, const float* __restrict__ s1,
                     const float* __restrict__ s2, u16* __restrict__ d0,
                     u16* __restrict__ d1, u16* __restrict__ d2) {
  int i = blockIdx.x * 256 + threadIdx.x;   // 3 * 3145728
  int which = i / 3145728;
  int j = i - which * 3145728;
  const float* s = (which == 0) ? s0 : (which == 1 ? s1 : s2);
  u16* d = (which == 0) ? d0 : (which == 1 ? d1 : d2);
  d[j] = f2b(s[j]);
}

__global__ void cvt2(const float* __restrict__ s0, const float* __restrict__ s1,
                     u16* __restrict__ d0, u16* __restrict__ d1) {
  int i = blockIdx.x * 256 + threadIdx.x;   // 2 * 1048576
  if (i < 1048576) d0[i] = f2b(s0[i]);
  else             d1[i - 1048576] = f2b(s1[i - 1048576]);
}

// Split g1_wih [3072, 642] (f32) into bf16 Wc [3072,512] and Wd [3072,192]
// (zero-padded cols 130..191 so K is a multiple of BK=32 twice over).
__global__ void prep_w1(const float* __restrict__ wih, u16* __restrict__ Wc, u16* __restrict__ Wd) {
  int i = blockIdx.x * 256 + threadIdx.x;
  const int NC = 3072 * 512;
  const int ND = 3072 * 192;
  if (i < NC) {
    int n = i >> 9, k = i & 511;
    Wc[i] = f2b(wih[n * 642 + k]);
  } else if (i < NC + ND) {
    int j = i - NC;
    int n = j / 192, k = j - n * 192;
    Wd[j] = (k < 130) ? f2b(wih[n * 642 + 512 + k]) : (u16)0;
  }
}

// fco_w [130,1024] f32 -> bf16 WBy [256,1024], zero rows 130..255
__global__ void prep_wby(const float* __restrict__ fcow, u16* __restrict__ wby) {
  int i = blockIdx.x * 256 + threadIdx.x;   // 256*1024
  int n = i >> 10;
  wby[i] = (n < 130) ? f2b(fcow[i]) : (u16)0;
}

// ---------------------------------------------------------------------------
// bt-GEMM: C[m][n] = sum_k A[m][k]*Bsel[n'][k].  A,B bf16.
//   Bsel/n' per 128-tile: n0<n_split -> B0,n'=n else B1,n'=n-n_split
// 128x128 tile, BK=32, 512 threads = 8 waves (4m x 2n of 32m x 64n, acc 2x4).
// r8: DOUBLE-BUFFERED global_load_lds (catalog T3 minimum 2-phase).
// r7 post-mortem: single-buffer gl16 serialized every K-step on the full
// load latency (issue -> vmcnt(0) -> barrier -> 80cyc compute), mode-3 GEMM
// 55->75us, MfmaUtil 2%. Fix: issue next tile's 2 gl16/wave into buf^1
// BEFORE ds_read+MFMA of buf, single __syncthreads (vmcnt0+barrier) at body
// END = issue-early/wait-late; latency hides under compute + 3 blocks/CU.
// LDS 32KB (no VGPR cost — unlike the r6 reg-dbuf that killed occupancy).
// Hazards: prefetch targets the buffer consumed 2 barriers ago; ds_read
// results consumed by MFMA before each barrier => one barrier/K-step is safe.
// mfma 16x16x32 bf16, fp32 accum (AGPR).
// UDA=true variant: A built from target[B=128,T=256,D=130] f32 with the
// prev-shift, reg-staged + ds_write into the same dbuf scheme; SEPARATE
// template instantiation so the hot kernel's regalloc isn't polluted.
//   tstep >= 0: M=2048, time step = tstep (fallback path)
//   tstep <  0: M=32768, row gm -> t = gm>>11, m2 = gm&2047 (precompute-all)
// Epilogue modes:
//  0: out0(bf16)[m*N+n] = acc + bias0[n]
//  1: t=tanh(acc+bias0[n]); n<1024 -> h1 else h2; write f32 (fout*) AND bf16 (out*)
//  2: out0(bf16)[m*N+n] = acc + b2f(addmat[(m&2047)*N+n])             [N=3072]
//  3: n<3072 -> out0+bias0 (gi2) ; else out1+bias1 (gh1)              [N=6144]
//  4: n<3072 -> out0+bias0 (gh2) ; 3072<=n<3202 -> y(f32) scatter     [N=3328]
// ---------------------------------------------------------------------------
template <bool UDA>
__global__ __launch_bounds__(512, 6) void gemm_bt(
    const u16* __restrict__ A, int lda, const float* __restrict__ dA,
    const u16* __restrict__ B0, const u16* __restrict__ B1, int ldb, int n_split,
    int N, int K, int mode, int tstep,
    const float* __restrict__ bias0, const float* __restrict__ bias1,
    u16* __restrict__ out0, u16* __restrict__ out1,
    const u16* __restrict__ addmat,
    float* __restrict__ fout0, float* __restrict__ fout1)
{
  __shared__ u16 As[2][128 * 32];
  __shared__ u16 Bs[2][128 * 32];

  const int tid = threadIdx.x;
  const int wave = tid >> 6;
  const int lane = tid & 63;
  const int m0 = blockIdx.y * 128;
  const int n0 = blockIdx.x * 128;
  const int wm = (wave & 3) * 32;    // wave m-offset (4 waves down)
  const int wn = (wave >> 2) * 64;   // wave n-offset (2 waves across)
  const int lr = lane & 15;
  const int lq = lane >> 4;

  const u16* Bsel;
  int nb0;
  if (n0 < n_split) { Bsel = B0; nb0 = n0; }
  else              { Bsel = B1; nb0 = n0 - n_split; }

  f32x4 acc[2][4] = {};

  // global_load_lds staging: wave w owns rows [w*16, w*16+16);
  // lane l -> row w*16 + (l>>2), 16B chunk (l&3)*8 elems. LDS dest is the
  // wave-uniform base &Xs[buf][w*512]; HW scatters base + lane*16 = linear.
  const int srow_g = wave * 16 + (lane >> 2);
  const int scol_g = (lane & 3) * 8;
  const u16* gB = &Bsel[(size_t)(nb0 + srow_g) * ldb + scol_g];
  const u16* gA = UDA ? nullptr : &A[(size_t)(m0 + srow_g) * lda + scol_g];

  // reg-staging coords for the UDA path (512 threads cover 128x32 tile)
  const int srow = tid >> 2;
  const int skc  = (tid & 3) * 8;

  // UDA A-source row (loop-invariant)
  const float* trow = nullptr;
  int tt = 0;
  if constexpr (UDA) {
    int mrow = m0 + srow;
    int t  = (tstep >= 0) ? tstep : (mrow >> 11);
    int m2 = mrow & 2047;
    int e = m2 >> 7, b = m2 & 127;
    tt = e * 16 + t;
    trow = dA + (size_t)(b * 256 + tt - 1) * 130;
  }

  auto stageA_uda = [&](u16* dst, int k0) {
    int kb = k0 + skc;
    u16x8 ra;
    if (tt > 0 && kb + 8 <= 130) {
#pragma unroll
      for (int q = 0; q < 4; ++q) {
        float2 v = *(const float2*)&trow[kb + 2 * q];
        ra[2 * q] = f2b(v.x); ra[2 * q + 1] = f2b(v.y);
      }
    } else {
#pragma unroll
      for (int j = 0; j < 8; ++j) {
        int k = kb + j;
        float v = (tt > 0 && k < 130) ? trow[k] : 0.f;
        ra[j] = f2b(v);
      }
    }
    *(u16x8*)&dst[srow * 32 + skc] = ra;
  };

  // --- prologue: stage tile 0 into buf 0 ---
  if constexpr (UDA) stageA_uda(As[0], 0);
  else               gl16(gA, &As[0][wave * 512]);
  gl16(gB, &Bs[0][wave * 512]);
  __syncthreads();

  const int nk = K >> 5;
  int cur = 0;
  for (int ks = 0; ks < nk; ++ks) {
    // issue-early: prefetch tile ks+1 into buf^1 (no wait here)
    if (ks + 1 < nk) {
      int k0n = (ks + 1) << 5;
      if constexpr (UDA) stageA_uda(As[cur ^ 1], k0n);
      else               gl16(gA + k0n, &As[cur ^ 1][wave * 512]);
      gl16(gB + k0n, &Bs[cur ^ 1][wave * 512]);
    }

    frag8 af[2], bfr[4];
#pragma unroll
    for (int i = 0; i < 2; ++i)
      af[i] = *(const frag8*)&As[cur][(wm + i * 16 + lr) * 32 + lq * 8];
#pragma unroll
    for (int j = 0; j < 4; ++j)
      bfr[j] = *(const frag8*)&Bs[cur][(wn + j * 16 + lr) * 32 + lq * 8];
#pragma unroll
    for (int i = 0; i < 2; ++i)
#pragma unroll
      for (int j = 0; j < 4; ++j)
        acc[i][j] = __builtin_amdgcn_mfma_f32_16x16x32_bf16(af[i], bfr[j], acc[i][j], 0, 0, 0);

    // wait-late: drains the prefetch (vmcnt0/lgkm0) + barrier, once per tile
    __syncthreads();
    cur ^= 1;
  }

  // C/D layout: col = lane&15 (n), row = (lane>>4)*4 + reg (m).
#pragma unroll
  for (int i = 0; i < 2; ++i) {
#pragma unroll
    for (int r = 0; r < 4; ++r) {
      int m = m0 + wm + i * 16 + lq * 4 + r;
#pragma unroll
      for (int j = 0; j < 4; ++j) {
        int n = n0 + wn + j * 16 + lr;
        float v = acc[i][j][r];
        if (mode == 0) {
          out0[(size_t)m * N + n] = f2b(v + bias0[n]);
        } else if (mode == 1) {
          float t = tanhf(v + bias0[n]);
          if (n < 1024) { fout0[(size_t)m * 1024 + n] = t;          out0[(size_t)m * 1024 + n] = f2b(t); }
          else          { fout1[(size_t)m * 1024 + (n - 1024)] = t; out1[(size_t)m * 1024 + (n - 1024)] = f2b(t); }
        } else if (mode == 2) {
          out0[(size_t)m * N + n] = f2b(v + b2f(addmat[(size_t)(m & 2047) * N + n]));
        } else if (mode == 3) {
          if (n < 3072) out0[(size_t)m * 3072 + n] = f2b(v + bias0[n]);
          else          out1[(size_t)m * 3072 + (n - 3072)] = f2b(v + bias1[n - 3072]);
        } else { // mode 4
          if (n < 3072) {
            out0[(size_t)m * 3072 + n] = f2b(v + bias0[n]);
          } else if (n < 3202) {
            int d = n - 3072;
            int b = m & 127, e = m >> 7;
            fout0[(size_t)((b << 8) + (e << 4) + tstep) * 130 + d] = v + bias1[d];
          }
        }
      }
    }
  }
}

// ---------------------------------------------------------------------------
// GRU combine: h = (1-z)*n + z*h. gi/gh bf16 [2048,3072] (biases folded),
// h32 f32 [2048,1024] master state (in place), hb16 bf16 shadow for GEMM A.
// ---------------------------------------------------------------------------
__global__ __launch_bounds__(256) void gru_combine(
    const u16* __restrict__ gi, const u16* __restrict__ gh,
    float* __restrict__ h32, u16* __restrict__ hb16)
{
  int idx = blockIdx.x * 256 + threadIdx.x;   // 0 .. 2048*128-1
  int m = idx >> 7;
  int j0 = (idx & 127) << 3;
  const size_t gb = (size_t)m * 3072 + j0;
  const size_t hb = (size_t)m * 1024 + j0;
  u16x8 ir = *(const u16x8*)&gi[gb];
  u16x8 iz = *(const u16x8*)&gi[gb + 1024];
  u16x8 in_ = *(const u16x8*)&gi[gb + 2048];
  u16x8 hr = *(const u16x8*)&gh[gb];
  u16x8 hz = *(const u16x8*)&gh[gb + 1024];
  u16x8 hn = *(const u16x8*)&gh[gb + 2048];
  f32x4 h0 = *(const f32x4*)&h32[hb];
  f32x4 h1v = *(const f32x4*)&h32[hb + 4];
  f32x4 o0, o1;
  u16x8 ob;
#pragma unroll
  for (int q = 0; q < 8; ++q) {
    float r = 1.f / (1.f + __expf(-(b2f(ir[q]) + b2f(hr[q]))));
    float z = 1.f / (1.f + __expf(-(b2f(iz[q]) + b2f(hz[q]))));
    float nn = tanhf(b2f(in_[q]) + r * b2f(hn[q]));
    float hh = (q < 4) ? h0[q & 3] : h1v[q & 3];
    float res = (1.f - z) * nn + z * hh;
    if (q < 4) o0[q & 3] = res; else o1[q & 3] = res;
    ob[q] = f2b(res);
  }
  *(f32x4*)&h32[hb] = o0;
  *(f32x4*)&h32[hb + 4] = o1;
  *(u16x8*)&hb16[hb] = ob;
}

// ---------------------------------------------------------------------------
extern "C" void kernel_launch(void* const* d_in, const int* in_sizes, int n_in,
                              void* d_out, int out_size, void* d_ws, size_t ws_size,
                              hipStream_t stream)
{
  const float* c      = (const float*)d_in[0];
  const float* target = (const float*)d_in[1];
  const float* fiw    = (const float*)d_in[4];
  const float* fib    = (const float*)d_in[5];
  const float* g1wih  = (const float*)d_in[6];
  const float* g1whh  = (const float*)d_in[7];
  const float* g1bih  = (const float*)d_in[8];
  const float* g1bhh  = (const float*)d_in[9];
  const float* g2wih  = (const float*)d_in[10];
  const float* g2whh  = (const float*)d_in[11];
  const float* g2bih  = (const float*)d_in[12];
  const float* g2bhh  = (const float*)d_in[13];
  const float* fcow   = (const float*)d_in[14];
  const float* fcob   = (const float*)d_in[15];
  float* out = (float*)d_out;

  char* wsp = (char*)d_ws;
  size_t off = 0;
  auto takeb = [&](size_t bytes) {
    void* p = (void*)(wsp + off);
    off += bytes;
    off = (off + 255) & ~(size_t)255;
    return p;
  };
  float* h1f = (float*)takeb((size_t)2048 * 1024 * 4);
  float* h2f = (float*)takeb((size_t)2048 * 1024 * 4);
  u16* h1b   = (u16*)takeb((size_t)2048 * 1024 * 2);
  u16* h2b   = (u16*)takeb((size_t)2048 * 1024 * 2);
  u16* gic   = (u16*)takeb((size_t)2048 * 3072 * 2);
  u16* gib   = (u16*)takeb((size_t)2048 * 3072 * 2);
  u16* gh1   = (u16*)takeb((size_t)2048 * 3072 * 2);
  u16* gh2   = (u16*)takeb((size_t)2048 * 3072 * 2);
  u16* cbf   = (u16*)takeb((size_t)2048 * 512 * 2);
  u16* Wfi   = (u16*)takeb((size_t)2048 * 512 * 2);
  u16* Wc    = (u16*)takeb((size_t)3072 * 512 * 2);
  u16* Wd    = (u16*)takeb((size_t)3072 * 192 * 2);
  u16* W1h   = (u16*)takeb((size_t)3072 * 1024 * 2);
  u16* W2i   = (u16*)takeb((size_t)3072 * 1024 * 2);
  u16* W2h   = (u16*)takeb((size_t)3072 * 1024 * 2);
  u16* WBy   = (u16*)takeb((size_t)256 * 1024 * 2);
  // base ~99 MiB. gi1_all (all 16 timesteps of gi1, teacher-forced so
  // h-independent) costs +192 MiB — take it only if ws allows.
  const size_t GI1_BYTES = (size_t)16 * 2048 * 3072 * 2;
  u16* gi1 = nullptr;
  if (ws_size >= off + GI1_BYTES + 256) gi1 = (u16*)takeb(GI1_BYTES);
  (void)in_sizes; (void)n_in; (void)out_size;

  const int BIG = 1 << 30;   // n_split sentinel: always B0

  // --- one-time prep: conversions to bf16 ---
  cvt2<<<8192, 256, 0, stream>>>(c, fiw, cbf, Wfi);
  cvt3<<<36864, 256, 0, stream>>>(g1whh, g2wih, g2whh, W1h, W2i, W2h);
  prep_w1 <<<8448, 256, 0, stream>>>(g1wih, Wc, Wd);
  prep_wby<<<1024, 256, 0, stream>>>(fcow, WBy);

  // --- init ---
  // h1,h2 = tanh(c @ fiw.T + fib)  (f32 + bf16 shadow)
  gemm_bt<false><<<dim3(16, 16), 512, 0, stream>>>(cbf, 512, nullptr, Wfi, nullptr, 512, BIG,
                                                   2048, 512, 1, 0, fib, nullptr,
                                                   h1b, h2b, nullptr, h1f, h2f);
  // gi_c = c @ Wc.T + g1bih
  gemm_bt<false><<<dim3(24, 16), 512, 0, stream>>>(cbf, 512, nullptr, Wc, nullptr, 512, BIG,
                                                   3072, 512, 0, 0, g1bih, nullptr,
                                                   gic, nullptr, nullptr, nullptr, nullptr);
  // gh1 = h1 @ g1whh.T + g1bhh
  gemm_bt<false><<<dim3(24, 16), 512, 0, stream>>>(h1b, 1024, nullptr, W1h, nullptr, 1024, BIG,
                                                   3072, 1024, 0, 0, g1bhh, nullptr,
                                                   gh1, nullptr, nullptr, nullptr, nullptr);
  // gh2 = h2 @ g2whh.T + g2bhh
  gemm_bt<false><<<dim3(24, 16), 512, 0, stream>>>(h2b, 1024, nullptr, W2h, nullptr, 1024, BIG,
                                                   3072, 1024, 0, 0, g2bhh, nullptr,
                                                   gh2, nullptr, nullptr, nullptr, nullptr);

  // gi1 for ALL t in one GEMM (M=32768): gi1_all[t*2048+m] = prev_t @ Wd.T + gic
  if (gi1 != nullptr) {
    gemm_bt<true><<<dim3(24, 256), 512, 0, stream>>>(nullptr, 192, target, Wd, nullptr, 192, BIG,
                                                     3072, 192, 2, -1, nullptr, nullptr,
                                                     gi1, nullptr, gic, nullptr, nullptr);
  }

  // --- recurrence ---
  for (int t = 0; t < 16; ++t) {
    const u16* gi1_t;
    if (gi1 != nullptr) {
      gi1_t = gi1 + (size_t)t * 2048 * 3072;
    } else {
      // fallback: per-step gi1 (A read directly from target, shifted)
      gemm_bt<true><<<dim3(24, 16), 512, 0, stream>>>(nullptr, 192, target, Wd, nullptr, 192, BIG,
                                                      3072, 192, 2, t, nullptr, nullptr,
                                                      gib, nullptr, gic, nullptr, nullptr);
      gi1_t = gib;
    }
    gru_combine<<<1024, 256, 0, stream>>>(gi1_t, gh1, h1f, h1b);   // h1 <- GRU1
    // gi2 = h1 @ g2wih.T + g2bih ; gh1_next = h1 @ g1whh.T + g1bhh
    gemm_bt<false><<<dim3(48, 16), 512, 0, stream>>>(h1b, 1024, nullptr, W2i, W1h, 1024, 3072,
                                                     6144, 1024, 3, 0, g2bih, g1bhh,
                                                     gib, gh1, nullptr, nullptr, nullptr);
    gru_combine<<<1024, 256, 0, stream>>>(gib, gh2, h2f, h2b);     // h2 <- GRU2
    // gh2_next = h2 @ g2whh.T + g2bhh ; y = h2 @ fco_w.T + fco_b -> out (f32)
    gemm_bt<false><<<dim3(26, 16), 512, 0, stream>>>(h2b, 1024, nullptr, W2h, WBy, 1024, 3072,
                                                     3328, 1024, 4, t, g2bhh, fcob,
                                                     gh2, nullptr, nullptr, out, nullptr);
  }
}

// Round 3
// 2042.781 us; speedup vs baseline: 1.2086x; 1.0115x over previous
//
#include <hip/hip_runtime.h>

typedef unsigned short u16;
typedef __attribute__((ext_vector_type(8))) short frag8;
typedef __attribute__((ext_vector_type(4))) float f32x4;
typedef __attribute__((ext_vector_type(8))) unsigned short u16x8;

// address-space typedefs for global_load_lds
typedef __attribute__((address_space(1))) const void GV;
typedef __attribute__((address_space(3))) void LV;

__device__ __forceinline__ void gl16(const u16* g, u16* l) {
  // async global->LDS, 16B per lane; LDS dest = wave-uniform base + lane*16
  __builtin_amdgcn_global_load_lds((GV*)g, (LV*)l, 16, 0, 0);
}

__device__ __forceinline__ float b2f(u16 u) {
  union { unsigned int i; float f; } v; v.i = ((unsigned int)u) << 16; return v.f;
}
__device__ __forceinline__ u16 f2b(float f) {
  union { float f; unsigned int i; } v; v.f = f;
  unsigned int x = v.i;
  x += 0x7fffu + ((x >> 16) & 1u);
  return (u16)(x >> 16);
}

// ---------------------------------------------------------------------------
// Prep kernels — f32 inputs; everything GEMM-facing becomes bf16 once here.
// ---------------------------------------------------------------------------
__global__ void cvt3(const float* __restrict__ s0, const float* __restrict__ s1,
                     const float* __restrict__ s2, u16* __restrict__ d0,
                     u16* __restrict__ d1, u16* __restrict__ d2) {
  int i = blockIdx.x * 256 + threadIdx.x;   // 3 * 3145728
  int which = i / 3145728;
  int j = i - which * 3145728;
  const float* s = (which == 0) ? s0 : (which == 1 ? s1 : s2);
  u16* d = (which == 0) ? d0 : (which == 1 ? d1 : d2);
  d[j] = f2b(s[j]);
}

__global__ void cvt2(const float* __restrict__ s0, const float* __restrict__ s1,
                     u16* __restrict__ d0, u16* __restrict__ d1) {
  int i = blockIdx.x * 256 + threadIdx.x;   // 2 * 1048576
  if (i < 1048576) d0[i] = f2b(s0[i]);
  else             d1[i - 1048576] = f2b(s1[i - 1048576]);
}

// Split g1_wih [3072, 642] (f32) into bf16 Wc [3072,512] and Wd [3072,192]
// (zero-padded cols 130..191 so K is a multiple of BK=32 twice over).
__global__ void prep_w1(const float* __restrict__ wih, u16* __restrict__ Wc, u16* __restrict__ Wd) {
  int i = blockIdx.x * 256 + threadIdx.x;
  const int NC = 3072 * 512;
  const int ND = 3072 * 192;
  if (i < NC) {
    int n = i >> 9, k = i & 511;
    Wc[i] = f2b(wih[n * 642 + k]);
  } else if (i < NC + ND) {
    int j = i - NC;
    int n = j / 192, k = j - n * 192;
    Wd[j] = (k < 130) ? f2b(wih[n * 642 + 512 + k]) : (u16)0;
  }
}

// fco_w [130,1024] f32 -> bf16 WBy [256,1024], zero rows 130..255
__global__ void prep_wby(const float* __restrict__ fcow, u16* __restrict__ wby) {
  int i = blockIdx.x * 256 + threadIdx.x;   // 256*1024
  int n = i >> 10;
  wby[i] = (n < 130) ? f2b(fcow[i]) : (u16)0;
}

// ---------------------------------------------------------------------------
// Shared GEMM machinery. 128x128 tile, BK=32, 512 threads = 8 waves
// (4m x 2n of 32m x 64n, acc 2x4), mfma 16x16x32 bf16, f32 accum.
//
// r9 K-loop: 3-buffer counted-vmcnt pipeline (catalog T4). r8's 2-buffer
// __syncthreads still drained vmcnt(0) every K-step (the ~20% structural
// stall; MfmaUtil 21%). Now: prologue issues tiles 0,1; iter k does
// s_waitcnt vmcnt(2) [tile k landed, tile k+1 in flight] -> s_barrier ->
// issue tile k+2 into buf (k+2)%3 -> ds_read/MFMA on buf k%3. Buffer safety:
// buf (k+2)%3 was last ds_read in iter k-1; the iter-k barrier orders all
// waves past that before the new gl16 lands. Uniform control flow (nk, k
// block-uniform) => legal barriers. sched_barrier(0) pins scheduling (rule
// 18). Last iter waits vmcnt(0).
//
// r9 swizzle (rule 21, both-sides-or-neither): the b128 frag read had 8
// consecutive lanes hitting rows r..r+7 chunk 0 = byte r*64 = 2 bank-quads
// only -> 4-way conflict (4.7M cyc/dispatch in r8). Fix: chunk' =
// chunk ^ ((row>>1)&3). gl16 dest stays LINEAR; the global SOURCE is
// pre-swizzled (chunk_g = (lane&3)^((lane>>3)&3), permutes within 64B
// segments so coalescing is preserved); reads use (lq^sw)*8, sw=(lr>>1)&3.
// quad = (4*row + chunk') mod 8 is bijective per 8-lane group -> conflict-free.
// ---------------------------------------------------------------------------
__device__ __forceinline__ void kloop3(
    const u16* gA, const u16* gB, int nk,
    u16* AsBase, u16* BsBase, int wave,
    int rdA, int rdB, f32x4 (&acc)[2][4])
{
  u16* Adst = AsBase + wave * 512;   // per-wave 16-row slab, linear dest
  u16* Bdst = BsBase + wave * 512;
  // prologue: tiles 0 and 1 in flight (nk >= 2 always here)
  gl16(gA,      Adst);        gl16(gB,      Bdst);
  gl16(gA + 32, Adst + 4096); gl16(gB + 32, Bdst + 4096);
  const u16* pA = gA + 64;
  const u16* pB = gB + 64;
  int cbuf = 0, nbuf = 2;
  for (int ks = 0; ks < nk; ++ks) {
    if (ks < nk - 1) asm volatile("s_waitcnt vmcnt(2)" : : : "memory");
    else             asm volatile("s_waitcnt vmcnt(0)" : : : "memory");
    __builtin_amdgcn_s_barrier();
    __builtin_amdgcn_sched_barrier(0);
    if (ks + 2 < nk) {
      gl16(pA, Adst + nbuf * 4096);
      gl16(pB, Bdst + nbuf * 4096);
      pA += 32; pB += 32;
    }
    const u16* Ab = AsBase + cbuf * 4096;
    const u16* Bb = BsBase + cbuf * 4096;
    frag8 af[2], bfr[4];
#pragma unroll
    for (int i = 0; i < 2; ++i)
      af[i] = *(const frag8*)&Ab[rdA + i * 512];
#pragma unroll
    for (int j = 0; j < 4; ++j)
      bfr[j] = *(const frag8*)&Bb[rdB + j * 512];
#pragma unroll
    for (int i = 0; i < 2; ++i)
#pragma unroll
      for (int j = 0; j < 4; ++j)
        acc[i][j] = __builtin_amdgcn_mfma_f32_16x16x32_bf16(af[i], bfr[j], acc[i][j], 0, 0, 0);
    cbuf = (cbuf == 2) ? 0 : cbuf + 1;
    nbuf = (nbuf == 2) ? 0 : nbuf + 1;
  }
}

// ---------------------------------------------------------------------------
// bt-GEMM (init / boundary / UDA): C[m][n] = sum_k A[m][k]*Bsel[n'][k].
//   Bsel/n' per 128-tile: n0<n_split -> B0,n'=n else B1,n'=n-n_split
// UDA=true: A built from target[B=128,T=256,D=130] f32 with the prev-shift,
// reg-staged + swizzled ds_write, 2-buffer __syncthreads loop (reg loads
// can't share the vmcnt count). tstep>=0: M=2048 at t=tstep; tstep<0:
// M=32768, row gm -> t=gm>>11, m2=gm&2047 (precompute-all).
// Epilogue modes:
//  0: out0(bf16)[m*N+n] = acc + bias0[n]
//  1: t=tanh(acc+bias0[n]); n<1024 -> h1 else h2; write f32 (fout*) AND bf16 (out*)
//  2: out0(bf16)[m*N+n] = acc + b2f(addmat[(m&2047)*N+n])             [N=3072]
//  3: n<3072 -> out0+bias0 (gi2) ; else out1+bias1 (gh1)              [N=6144]
//  4: n<3072 -> out0+bias0 (gh2) ; 3072<=n<3202 -> y(f32) scatter     [N=3328]
// ---------------------------------------------------------------------------
template <bool UDA>
__global__ __launch_bounds__(512, 6) void gemm_bt(
    const u16* __restrict__ A, int lda, const float* __restrict__ dA,
    const u16* __restrict__ B0, const u16* __restrict__ B1, int ldb, int n_split,
    int N, int K, int mode, int tstep,
    const float* __restrict__ bias0, const float* __restrict__ bias1,
    u16* __restrict__ out0, u16* __restrict__ out1,
    const u16* __restrict__ addmat,
    float* __restrict__ fout0, float* __restrict__ fout1)
{
  __shared__ u16 As[3 * 4096];
  __shared__ u16 Bs[3 * 4096];

  const int tid = threadIdx.x;
  const int wave = tid >> 6;
  const int lane = tid & 63;
  const int m0 = blockIdx.y * 128;
  const int n0 = blockIdx.x * 128;
  const int wm = (wave & 3) * 32;
  const int wn = (wave >> 2) * 64;
  const int lr = lane & 15;
  const int lq = lane >> 4;
  const int sw = (lr >> 1) & 3;                  // read-side swizzle
  const int rdA = (wm + lr) * 32 + ((lq ^ sw) << 3);
  const int rdB = (wn + lr) * 32 + ((lq ^ sw) << 3);

  const u16* Bsel;
  int nb0;
  if (n0 < n_split) { Bsel = B0; nb0 = n0; }
  else              { Bsel = B1; nb0 = n0 - n_split; }

  f32x4 acc[2][4] = {};

  // staging source coords: row = wave*16 + (lane>>2), pre-swizzled chunk
  const int srow_g = wave * 16 + (lane >> 2);
  const int scol_g = (((lane & 3) ^ ((lane >> 3) & 3)) << 3);
  const u16* gB = &Bsel[(size_t)(nb0 + srow_g) * ldb + scol_g];

  const int nk = K >> 5;

  if constexpr (!UDA) {
    const u16* gA = &A[(size_t)(m0 + srow_g) * lda + scol_g];
    kloop3(gA, gB, nk, As, Bs, wave, rdA, rdB, acc);
  } else {
    // reg-staging coords (512 threads cover 128x32 tile)
    const int srow = tid >> 2;
    const int skc  = (tid & 3) * 8;                          // global chunk
    const int swr  = ((tid & 3) ^ ((tid >> 3) & 3)) * 8;     // swizzled LDS chunk
    const float* trow = nullptr;
    int tt = 0;
    {
      int mrow = m0 + srow;
      int t  = (tstep >= 0) ? tstep : (mrow >> 11);
      int m2 = mrow & 2047;
      int e = m2 >> 7, b = m2 & 127;
      tt = e * 16 + t;
      trow = dA + (size_t)(b * 256 + tt - 1) * 130;
    }
    auto stageA_uda = [&](u16* dst, int k0) {
      int kb = k0 + skc;
      u16x8 ra;
      if (tt > 0 && kb + 8 <= 130) {
#pragma unroll
        for (int q = 0; q < 4; ++q) {
          float2 v = *(const float2*)&trow[kb + 2 * q];
          ra[2 * q] = f2b(v.x); ra[2 * q + 1] = f2b(v.y);
        }
      } else {
#pragma unroll
        for (int j = 0; j < 8; ++j) {
          int k = kb + j;
          float v = (tt > 0 && k < 130) ? trow[k] : 0.f;
          ra[j] = f2b(v);
        }
      }
      *(u16x8*)&dst[srow * 32 + swr] = ra;
    };

    // 2-buffer __syncthreads pipeline (r8 structure)
    stageA_uda(As, 0);
    gl16(gB, &Bs[wave * 512]);
    __syncthreads();
    int cur = 0;
    for (int ks = 0; ks < nk; ++ks) {
      if (ks + 1 < nk) {
        stageA_uda(As + (cur ^ 1) * 4096, (ks + 1) << 5);
        gl16(gB + ((ks + 1) << 5), &Bs[(cur ^ 1) * 4096 + wave * 512]);
      }
      const u16* Ab = As + cur * 4096;
      const u16* Bb = Bs + cur * 4096;
      frag8 af[2], bfr[4];
#pragma unroll
      for (int i = 0; i < 2; ++i)
        af[i] = *(const frag8*)&Ab[rdA + i * 512];
#pragma unroll
      for (int j = 0; j < 4; ++j)
        bfr[j] = *(const frag8*)&Bb[rdB + j * 512];
#pragma unroll
      for (int i = 0; i < 2; ++i)
#pragma unroll
        for (int j = 0; j < 4; ++j)
          acc[i][j] = __builtin_amdgcn_mfma_f32_16x16x32_bf16(af[i], bfr[j], acc[i][j], 0, 0, 0);
      __syncthreads();
      cur ^= 1;
    }
  }

  // C/D layout: col = lane&15 (n), row = (lane>>4)*4 + reg (m).
#pragma unroll
  for (int i = 0; i < 2; ++i) {
#pragma unroll
    for (int r = 0; r < 4; ++r) {
      int m = m0 + wm + i * 16 + lq * 4 + r;
#pragma unroll
      for (int j = 0; j < 4; ++j) {
        int n = n0 + wn + j * 16 + lr;
        float v = acc[i][j][r];
        if (mode == 0) {
          out0[(size_t)m * N + n] = f2b(v + bias0[n]);
        } else if (mode == 1) {
          float t = tanhf(v + bias0[n]);
          if (n < 1024) { fout0[(size_t)m * 1024 + n] = t;          out0[(size_t)m * 1024 + n] = f2b(t); }
          else          { fout1[(size_t)m * 1024 + (n - 1024)] = t; out1[(size_t)m * 1024 + (n - 1024)] = f2b(t); }
        } else if (mode == 2) {
          out0[(size_t)m * N + n] = f2b(v + b2f(addmat[(size_t)(m & 2047) * N + n]));
        } else if (mode == 3) {
          if (n < 3072) out0[(size_t)m * 3072 + n] = f2b(v + bias0[n]);
          else          out1[(size_t)m * 3072 + (n - 3072)] = f2b(v + bias1[n - 3072]);
        } else { // mode 4
          if (n < 3072) {
            out0[(size_t)m * 3072 + n] = f2b(v + bias0[n]);
          } else if (n < 3202) {
            int d = n - 3072;
            int b = m & 127, e = m >> 7;
            fout0[(size_t)((b << 8) + (e << 4) + tstep) * 130 + d] = v + bias1[d];
          }
        }
      }
    }
  }
}

// ---------------------------------------------------------------------------
// Fused step GEMM: gemm3(t) [gi2 = h1@W2i ; gh1' = h1@W1h] and gemm4(t-1)
// [gh2' = h2@W2h ; y = h2@WBy] in ONE dispatch. N = 9472 -> 74 x-blocks x 16
// = 1184 blocks (vs 768-then-416 sequential: no idle-CU tail, one launch).
// Regions by n0: [0,3072) gi2 | [3072,6144) gh1 | [6144,9216) gh2 |
// [9216,9472) y (WBy zero-padded to 256 rows, scatter cols <130).
// K = 1024, lda = ldb = 1024 for all regions.
// ---------------------------------------------------------------------------
__global__ __launch_bounds__(512, 6) void gemm_fused(
    const u16* __restrict__ A1, const u16* __restrict__ A2,
    const u16* __restrict__ W2i, const u16* __restrict__ W1h,
    const u16* __restrict__ W2h, const u16* __restrict__ WBy,
    const float* __restrict__ b_gi2, const float* __restrict__ b_gh1,
    const float* __restrict__ b_gh2, const float* __restrict__ b_y,
    u16* __restrict__ gi2, u16* __restrict__ gh1, u16* __restrict__ gh2,
    float* __restrict__ y, int tstep)
{
  __shared__ u16 As[3 * 4096];
  __shared__ u16 Bs[3 * 4096];

  const int tid = threadIdx.x;
  const int wave = tid >> 6;
  const int lane = tid & 63;
  const int m0 = blockIdx.y * 128;
  const int n0 = blockIdx.x * 128;
  const int wm = (wave & 3) * 32;
  const int wn = (wave >> 2) * 64;
  const int lr = lane & 15;
  const int lq = lane >> 4;
  const int sw = (lr >> 1) & 3;
  const int rdA = (wm + lr) * 32 + ((lq ^ sw) << 3);
  const int rdB = (wn + lr) * 32 + ((lq ^ sw) << 3);

  const int reg = (n0 >= 9216) ? 3 : (n0 / 3072);
  const int nb0 = n0 - reg * 3072;
  const u16* A  = (reg < 2) ? A1 : A2;
  const u16* Bw = (reg == 0) ? W2i : (reg == 1) ? W1h : (reg == 2) ? W2h : WBy;
  const float* bias = (reg == 0) ? b_gi2 : (reg == 1) ? b_gh1 : (reg == 2) ? b_gh2 : b_y;

  const int srow_g = wave * 16 + (lane >> 2);
  const int scol_g = (((lane & 3) ^ ((lane >> 3) & 3)) << 3);
  const u16* gA = &A[(size_t)(m0 + srow_g) * 1024 + scol_g];
  const u16* gB = &Bw[(size_t)(nb0 + srow_g) * 1024 + scol_g];

  f32x4 acc[2][4] = {};
  kloop3(gA, gB, 32, As, Bs, wave, rdA, rdB, acc);

#pragma unroll
  for (int i = 0; i < 2; ++i) {
#pragma unroll
    for (int r = 0; r < 4; ++r) {
      int m = m0 + wm + i * 16 + lq * 4 + r;
#pragma unroll
      for (int j = 0; j < 4; ++j) {
        int nl = nb0 + wn + j * 16 + lr;
        float v = acc[i][j][r];
        if (reg == 0)      gi2[(size_t)m * 3072 + nl] = f2b(v + bias[nl]);
        else if (reg == 1) gh1[(size_t)m * 3072 + nl] = f2b(v + bias[nl]);
        else if (reg == 2) gh2[(size_t)m * 3072 + nl] = f2b(v + bias[nl]);
        else if (nl < 130) {
          int b = m & 127, e = m >> 7;
          y[(size_t)((b << 8) + (e << 4) + tstep) * 130 + nl] = v + bias[nl];
        }
      }
    }
  }
}

// ---------------------------------------------------------------------------
// Fused GRU combine: slot A = combine1(t) [h1 <- GRU1], slot B =
// combine2(t-1) [h2 <- GRU2]. Both ready after the preceding fused GEMM.
// h = (1-z)*n + z*h; gi/gh bf16 [2048,3072] (biases folded), h32 f32 master,
// hb16 bf16 shadow for GEMM A.
// ---------------------------------------------------------------------------
__global__ __launch_bounds__(256) void gru2(
    const u16* __restrict__ giA, const u16* __restrict__ ghA,
    float* __restrict__ hA, u16* __restrict__ hbA,
    const u16* __restrict__ giB, const u16* __restrict__ ghB,
    float* __restrict__ hB, u16* __restrict__ hbB,
    int doA, int doB)
{
  int blk = blockIdx.x;
  const u16 *gi, *gh; float* h32; u16* hb16;
  if (blk < 1024) { if (!doA) return; gi = giA; gh = ghA; h32 = hA; hb16 = hbA; }
  else { if (!doB) return; gi = giB; gh = ghB; h32 = hB; hb16 = hbB; blk -= 1024; }
  int idx = blk * 256 + threadIdx.x;   // 0 .. 2048*128-1
  int m = idx >> 7;
  int j0 = (idx & 127) << 3;
  const size_t gb = (size_t)m * 3072 + j0;
  const size_t hb = (size_t)m * 1024 + j0;
  u16x8 ir = *(const u16x8*)&gi[gb];
  u16x8 iz = *(const u16x8*)&gi[gb + 1024];
  u16x8 in_ = *(const u16x8*)&gi[gb + 2048];
  u16x8 hr = *(const u16x8*)&gh[gb];
  u16x8 hz = *(const u16x8*)&gh[gb + 1024];
  u16x8 hn = *(const u16x8*)&gh[gb + 2048];
  f32x4 h0 = *(const f32x4*)&h32[hb];
  f32x4 h1v = *(const f32x4*)&h32[hb + 4];
  f32x4 o0, o1;
  u16x8 ob;
#pragma unroll
  for (int q = 0; q < 8; ++q) {
    float r = 1.f / (1.f + __expf(-(b2f(ir[q]) + b2f(hr[q]))));
    float z = 1.f / (1.f + __expf(-(b2f(iz[q]) + b2f(hz[q]))));
    float nn = tanhf(b2f(in_[q]) + r * b2f(hn[q]));
    float hh = (q < 4) ? h0[q & 3] : h1v[q & 3];
    float res = (1.f - z) * nn + z * hh;
    if (q < 4) o0[q & 3] = res; else o1[q & 3] = res;
    ob[q] = f2b(res);
  }
  *(f32x4*)&h32[hb] = o0;
  *(f32x4*)&h32[hb + 4] = o1;
  *(u16x8*)&hb16[hb] = ob;
}

// ---------------------------------------------------------------------------
extern "C" void kernel_launch(void* const* d_in, const int* in_sizes, int n_in,
                              void* d_out, int out_size, void* d_ws, size_t ws_size,
                              hipStream_t stream)
{
  const float* c      = (const float*)d_in[0];
  const float* target = (const float*)d_in[1];
  const float* fiw    = (const float*)d_in[4];
  const float* fib    = (const float*)d_in[5];
  const float* g1wih  = (const float*)d_in[6];
  const float* g1whh  = (const float*)d_in[7];
  const float* g1bih  = (const float*)d_in[8];
  const float* g1bhh  = (const float*)d_in[9];
  const float* g2wih  = (const float*)d_in[10];
  const float* g2whh  = (const float*)d_in[11];
  const float* g2bih  = (const float*)d_in[12];
  const float* g2bhh  = (const float*)d_in[13];
  const float* fcow   = (const float*)d_in[14];
  const float* fcob   = (const float*)d_in[15];
  float* out = (float*)d_out;

  char* wsp = (char*)d_ws;
  size_t off = 0;
  auto takeb = [&](size_t bytes) {
    void* p = (void*)(wsp + off);
    off += bytes;
    off = (off + 255) & ~(size_t)255;
    return p;
  };
  float* h1f = (float*)takeb((size_t)2048 * 1024 * 4);
  float* h2f = (float*)takeb((size_t)2048 * 1024 * 4);
  u16* h1b   = (u16*)takeb((size_t)2048 * 1024 * 2);
  u16* h2b   = (u16*)takeb((size_t)2048 * 1024 * 2);
  u16* gic   = (u16*)takeb((size_t)2048 * 3072 * 2);
  u16* gib   = (u16*)takeb((size_t)2048 * 3072 * 2);
  u16* gh1   = (u16*)takeb((size_t)2048 * 3072 * 2);
  u16* gh2   = (u16*)takeb((size_t)2048 * 3072 * 2);
  u16* cbf   = (u16*)takeb((size_t)2048 * 512 * 2);
  u16* Wfi   = (u16*)takeb((size_t)2048 * 512 * 2);
  u16* Wc    = (u16*)takeb((size_t)3072 * 512 * 2);
  u16* Wd    = (u16*)takeb((size_t)3072 * 192 * 2);
  u16* W1h   = (u16*)takeb((size_t)3072 * 1024 * 2);
  u16* W2i   = (u16*)takeb((size_t)3072 * 1024 * 2);
  u16* W2h   = (u16*)takeb((size_t)3072 * 1024 * 2);
  u16* WBy   = (u16*)takeb((size_t)256 * 1024 * 2);
  // base ~99 MiB. gi1_all (all 16 timesteps of gi1, teacher-forced so
  // h-independent) costs +192 MiB — take it only if ws allows.
  const size_t GI1_BYTES = (size_t)16 * 2048 * 3072 * 2;
  u16* gi1 = nullptr;
  if (ws_size >= off + GI1_BYTES + 256) gi1 = (u16*)takeb(GI1_BYTES);
  (void)in_sizes; (void)n_in; (void)out_size;

  const int BIG = 1 << 30;   // n_split sentinel: always B0

  // --- one-time prep: conversions to bf16 ---
  cvt2<<<8192, 256, 0, stream>>>(c, fiw, cbf, Wfi);
  cvt3<<<36864, 256, 0, stream>>>(g1whh, g2wih, g2whh, W1h, W2i, W2h);
  prep_w1 <<<8448, 256, 0, stream>>>(g1wih, Wc, Wd);
  prep_wby<<<1024, 256, 0, stream>>>(fcow, WBy);

  // --- init ---
  // h1,h2 = tanh(c @ fiw.T + fib)  (f32 + bf16 shadow)
  gemm_bt<false><<<dim3(16, 16), 512, 0, stream>>>(cbf, 512, nullptr, Wfi, nullptr, 512, BIG,
                                                   2048, 512, 1, 0, fib, nullptr,
                                                   h1b, h2b, nullptr, h1f, h2f);
  // gi_c = c @ Wc.T + g1bih
  gemm_bt<false><<<dim3(24, 16), 512, 0, stream>>>(cbf, 512, nullptr, Wc, nullptr, 512, BIG,
                                                   3072, 512, 0, 0, g1bih, nullptr,
                                                   gic, nullptr, nullptr, nullptr, nullptr);
  // gh1 = h1 @ g1whh.T + g1bhh
  gemm_bt<false><<<dim3(24, 16), 512, 0, stream>>>(h1b, 1024, nullptr, W1h, nullptr, 1024, BIG,
                                                   3072, 1024, 0, 0, g1bhh, nullptr,
                                                   gh1, nullptr, nullptr, nullptr, nullptr);
  // gh2 = h2 @ g2whh.T + g2bhh
  gemm_bt<false><<<dim3(24, 16), 512, 0, stream>>>(h2b, 1024, nullptr, W2h, nullptr, 1024, BIG,
                                                   3072, 1024, 0, 0, g2bhh, nullptr,
                                                   gh2, nullptr, nullptr, nullptr, nullptr);

  if (gi1 != nullptr) {
    // gi1 for ALL t in one GEMM (M=32768): gi1_all[t*2048+m] = prev_t @ Wd.T + gic
    gemm_bt<true><<<dim3(24, 256), 512, 0, stream>>>(nullptr, 192, target, Wd, nullptr, 192, BIG,
                                                     3072, 192, 2, -1, nullptr, nullptr,
                                                     gi1, nullptr, gic, nullptr, nullptr);

    // --- recurrence: alternating C(t) -> G(t), 2 dispatches per step ---
    // C(0): combine1(0) only
    gru2<<<2048, 256, 0, stream>>>(gi1, gh1, h1f, h1b, nullptr, nullptr, nullptr, nullptr, 1, 0);
    // G(0): gemm3(0) only
    gemm_bt<false><<<dim3(48, 16), 512, 0, stream>>>(h1b, 1024, nullptr, W2i, W1h, 1024, 3072,
                                                     6144, 1024, 3, 0, g2bih, g1bhh,
                                                     gib, gh1, nullptr, nullptr, nullptr);
    for (int t = 1; t < 16; ++t) {
      // C(t): combine1(t) [gi1_t, gh1] + combine2(t-1) [gi2, gh2]
      gru2<<<2048, 256, 0, stream>>>(gi1 + (size_t)t * 2048 * 3072, gh1, h1f, h1b,
                                     gib, gh2, h2f, h2b, 1, 1);
      // G(t): gemm3(t) + gemm4(t-1); y uses tstep = t-1
      gemm_fused<<<dim3(74, 16), 512, 0, stream>>>(h1b, h2b, W2i, W1h, W2h, WBy,
                                                   g2bih, g1bhh, g2bhh, fcob,
                                                   gib, gh1, gh2, out, t - 1);
    }
    // C(16): combine2(15) only
    gru2<<<2048, 256, 0, stream>>>(nullptr, nullptr, nullptr, nullptr,
                                   gib, gh2, h2f, h2b, 0, 1);
    // G(16): gemm4(15): gh2' (discarded) + y(15)
    gemm_bt<false><<<dim3(26, 16), 512, 0, stream>>>(h2b, 1024, nullptr, W2h, WBy, 1024, 3072,
                                                     3328, 1024, 4, 15, g2bhh, fcob,
                                                     gh2, nullptr, nullptr, out, nullptr);
  } else {
    // fallback (small ws): r8-style per-step sequence
    for (int t = 0; t < 16; ++t) {
      gemm_bt<true><<<dim3(24, 16), 512, 0, stream>>>(nullptr, 192, target, Wd, nullptr, 192, BIG,
                                                      3072, 192, 2, t, nullptr, nullptr,
                                                      gib, nullptr, gic, nullptr, nullptr);
      gru2<<<2048, 256, 0, stream>>>(gib, gh1, h1f, h1b, nullptr, nullptr, nullptr, nullptr, 1, 0);
      gemm_bt<false><<<dim3(48, 16), 512, 0, stream>>>(h1b, 1024, nullptr, W2i, W1h, 1024, 3072,
                                                       6144, 1024, 3, 0, g2bih, g1bhh,
                                                       gib, gh1, nullptr, nullptr, nullptr);
      gru2<<<2048, 256, 0, stream>>>(gib, gh2, h2f, h2b, nullptr, nullptr, nullptr, nullptr, 1, 0);
      gemm_bt<false><<<dim3(26, 16), 512, 0, stream>>>(h2b, 1024, nullptr, W2h, WBy, 1024, 3072,
                                                       3328, 1024, 4, t, g2bhh, fcob,
                                                       gh2, nullptr, nullptr, out, nullptr);
    }
  }
}